// Round 10
// baseline (1761.893 us; speedup 1.0000x reference)
//
#include <hip/hip_runtime.h>

#define DD 32
#define NEG_SLOPE 0.01f
#define BN_EPS 1e-5f
#define SB 256          // stats partial blocks
#define BKL 128         // nodes per dst-bucket
#define EBLK 256        // edge blocks for counting sort
#define MAXBUK 800      // LDS counter capacity (NBUK must fit)

typedef unsigned short u16;
typedef unsigned int u32;

__device__ __forceinline__ u16 f32_to_bf16(float f) {   // RNE
    u32 u = __float_as_uint(f);
    return (u16)((u + 0x7FFFu + ((u >> 16) & 1u)) >> 16);
}
__device__ __forceinline__ float bf16_to_f32(u16 b) {
    return __uint_as_float(((u32)b) << 16);
}

// ======================= helpers ===========================================

__global__ void zero_kernel(float* p, int n) {
    int i = blockIdx.x * blockDim.x + threadIdx.x;
    if (i < n) p[i] = 0.0f;
}
__global__ void cvt_bf16_kernel(const float* __restrict__ x, u16* __restrict__ xb, int n) {
    int i = blockIdx.x * blockDim.x + threadIdx.x;
    if (i < n) xb[i] = f32_to_bf16(x[i]);
}

// ======================= bucketed counting sort ============================
// Pass A: counts, bucket-major: countsT[buk*EBLK + eb]
__global__ void count_kernel(const int* __restrict__ dst, int* __restrict__ countsT,
                             int E, int EPB, int NBUK) {
    __shared__ int cnt[MAXBUK];
    int eb = blockIdx.x;
    for (int i = threadIdx.x; i < NBUK; i += blockDim.x) cnt[i] = 0;
    __syncthreads();
    int lo = eb * EPB;
    int hi = lo + EPB; if (hi > E) hi = E;
    for (int e = lo + threadIdx.x; e < hi; e += blockDim.x)
        atomicAdd(&cnt[dst[e] >> 7], 1);          // BKL=128
    __syncthreads();
    for (int i = threadIdx.x; i < NBUK; i += blockDim.x)
        countsT[i * EBLK + eb] = cnt[i];
}

// Pass B: in-place exclusive scan over TOTC=NBUK*EBLK ints
__global__ void scan_block_kernel(const int* deg, int* pre, int* bsum, int N) {
    __shared__ int sh[1024];
    int tid = threadIdx.x;
    int i = blockIdx.x * 1024 + tid;
    int v = (i < N) ? deg[i] : 0;
    sh[tid] = v;
    __syncthreads();
    for (int off = 1; off < 1024; off <<= 1) {
        int t = (tid >= off) ? sh[tid - off] : 0;
        __syncthreads();
        sh[tid] += t;
        __syncthreads();
    }
    if (i < N) pre[i] = sh[tid] - v;              // exclusive
    if (tid == 1023) bsum[blockIdx.x] = sh[1023];
}

__global__ void scan_sums256(const int* bsum, int* boff, int nb) {
    __shared__ int sh[256];
    int tid = threadIdx.x;
    int v = (tid < nb) ? bsum[tid] : 0;
    sh[tid] = v;
    __syncthreads();
    for (int off = 1; off < 256; off <<= 1) {
        int t = (tid >= off) ? sh[tid - off] : 0;
        __syncthreads();
        sh[tid] += t;
        __syncthreads();
    }
    if (tid < nb) boff[tid] = sh[tid] - v;        // exclusive
}

__global__ void add_flat_kernel(int* a, const int* boff, int n) {
    int i = blockIdx.x * blockDim.x + threadIdx.x;
    if (i < n) a[i] += boff[i >> 10];
}

// Pass C: scatter into per-(block,bucket) contiguous shards (amplification-free)
// pack: q.x = (dst_low7 << 20) | src   (needs N <= 2^20), q.y = bits(w)
__global__ void shard_kernel(const int* __restrict__ src, const int* __restrict__ dst,
                             const float* __restrict__ ew, const int* __restrict__ scanT,
                             int2* __restrict__ perm2, int E, int EPB, int NBUK) {
    __shared__ int cur[MAXBUK];
    int eb = blockIdx.x;
    for (int i = threadIdx.x; i < NBUK; i += blockDim.x)
        cur[i] = scanT[i * EBLK + eb];
    __syncthreads();
    int lo = eb * EPB;
    int hi = lo + EPB; if (hi > E) hi = E;
    for (int e = lo + threadIdx.x; e < hi; e += blockDim.x) {
        int d = dst[e];
        int slot = atomicAdd(&cur[d >> 7], 1);
        int2 q;
        q.x = ((d & (BKL - 1)) << 20) | src[e];
        q.y = __float_as_int(ew[e]);
        perm2[slot] = q;
    }
}

// ======================= LDS-scatter propagation ===========================
// block b owns nodes [b*BKL, (b+1)*BKL); streams its bucket's edges;
// LDS f32 accumulators; bank = lane -> conflict-free; coalesced row writes.
template <bool EMIT>
__global__ void prop_lds_kernel(const u16* __restrict__ xb, const int* __restrict__ scanT,
                                const int2* __restrict__ perm2,
                                float* __restrict__ out, u16* __restrict__ outb,
                                int N, int E, int NBUK) {
    __shared__ float acc[BKL * DD];               // 16 KB
    int b = blockIdx.x;
    for (int i = threadIdx.x; i < BKL * DD; i += blockDim.x) acc[i] = 0.f;
    __syncthreads();
    int qlo = scanT[b * EBLK];
    int qhi = (b + 1 < NBUK) ? scanT[(b + 1) * EBLK] : E;
    int g = threadIdx.x >> 5, c = threadIdx.x & 31;
    for (int j = qlo + g; j < qhi; j += 8) {
        int2 q = perm2[j];                        // broadcast within 32-lane group
        int   s  = q.x & 0xFFFFF;
        int   dl = q.x >> 20;
        float w  = __int_as_float(q.y);
        atomicAdd(&acc[dl * DD + c], w * bf16_to_f32(xb[s * DD + c]));
    }
    __syncthreads();
    for (int i = g; i < BKL; i += 8) {
        int node = b * BKL + i;
        if (node < N) {
            float v = acc[i * DD + c];
            out[node * DD + c] = v;
            if (EMIT) outb[node * DD + c] = f32_to_bf16(v);
        }
    }
}

// ======================= combine v3 (registers, proven round 6) ============
// out[n][c] = sum_d x0*W0[d][c] + x1*W1[d][c] + x2*W2[d][c]
// (bias dropped: BN mean-subtraction cancels per-column constants exactly)
// In-place on x0 safe: a thread's row loads all precede its single store.
__global__ void combine_v3(const float* x0, const float* __restrict__ x1,
                           const float* __restrict__ x2, const float* __restrict__ W,
                           float* out, int N) {
    int c = threadIdx.x & 31;
    float w0[DD], w1[DD], w2[DD];
#pragma unroll
    for (int d = 0; d < DD; ++d) {
        w0[d] = W[d * DD + c];
        w1[d] = W[DD * DD + d * DD + c];
        w2[d] = W[2 * DD * DD + d * DD + c];
    }
    int group   = (blockIdx.x * blockDim.x + threadIdx.x) >> 5;
    int ngroups = (gridDim.x * blockDim.x) >> 5;
    for (int n = group; n < N; n += ngroups) {
        const float4* r0 = reinterpret_cast<const float4*>(x0 + (size_t)n * DD);
        const float4* r1 = reinterpret_cast<const float4*>(x1 + (size_t)n * DD);
        const float4* r2 = reinterpret_cast<const float4*>(x2 + (size_t)n * DD);
        float acc = 0.f;
#pragma unroll
        for (int q = 0; q < DD / 4; ++q) {
            float4 v0 = r0[q];
            float4 v1 = r1[q];
            float4 v2 = r2[q];
            acc += v0.x * w0[4*q] + v0.y * w0[4*q+1] + v0.z * w0[4*q+2] + v0.w * w0[4*q+3];
            acc += v1.x * w1[4*q] + v1.y * w1[4*q+1] + v1.z * w1[4*q+2] + v1.w * w1[4*q+3];
            acc += v2.x * w2[4*q] + v2.y * w2[4*q+1] + v2.z * w2[4*q+2] + v2.w * w2[4*q+3];
        }
        out[(size_t)n * DD + c] = acc;
    }
}

// ======================= stats + bnrelu (proven) ===========================

__global__ void stats_part_kernel(const float* x, float* part, int total) {
    int tid = threadIdx.x;
    int idx = blockIdx.x * 256 + tid;
    const int stride = SB * 256;
    float s = 0.f, ss = 0.f;
    for (int i = idx; i < total; i += stride) { float v = x[i]; s += v; ss += v * v; }
    __shared__ float sh[2][8][DD];
    sh[0][tid >> 5][tid & 31] = s;
    sh[1][tid >> 5][tid & 31] = ss;
    __syncthreads();
    if (tid < DD) {
        float ts = 0.f, tss = 0.f;
        for (int g = 0; g < 8; ++g) { ts += sh[0][g][tid]; tss += sh[1][g][tid]; }
        part[blockIdx.x * 64 + tid] = ts;
        part[blockIdx.x * 64 + DD + tid] = tss;
    }
}

__global__ void stats_final_kernel(const float* part, float* st) {
    int tid = threadIdx.x;                        // 64 threads
    if (tid < 64) {
        float a = 0.f;
        for (int b = 0; b < SB; ++b) a += part[b * 64 + tid];
        st[tid] = a;
    }
}

template <bool EMIT>
__global__ void bnrelu_kernel(const float* x, const float* stats,
                              const float* gamma, const float* beta,
                              float* out, u16* outb, int total, float invN) {
    int i = blockIdx.x * blockDim.x + threadIdx.x;
    if (i >= total) return;
    int c = i & 31;
    float m   = stats[c] * invN;
    float msq = stats[DD + c] * invN;
    float var = msq - m * m;
    float inv = 1.0f / sqrtf(var + BN_EPS);
    float v = (x[i] - m) * inv * gamma[c] + beta[c];
    v = v >= 0.f ? v : NEG_SLOPE * v;
    out[i] = v;
    if (EMIT) outb[i] = f32_to_bf16(v);
}

// ======================= fallback path (round-3, proven) ===================

__global__ void prop_kernel(const float* x, const int* src, const int* dst,
                            const float* ew, float* out, int E) {
    int t = blockIdx.x * blockDim.x + threadIdx.x;
    int e = t >> 5;
    if (e >= E) return;
    int c = t & 31;
    float v = ew[e] * x[src[e] * DD + c];
    atomicAdd(&out[dst[e] * DD + c], v);
}

__global__ void combine_basic(const float* x0, const float* x1, const float* x2,
                              const float* W, const float* bias,
                              float* out, int N) {
    int t = blockIdx.x * blockDim.x + threadIdx.x;
    int n = t >> 5;
    if (n >= N) return;
    int c = t & 31;
    const float* r0 = x0 + n * DD;
    const float* r1 = x1 + n * DD;
    const float* r2 = x2 + n * DD;
    float acc = bias[c];
    for (int d = 0; d < DD; ++d) {
        acc += r0[d] * W[d * DD + c];
        acc += r1[d] * W[DD * DD + d * DD + c];
        acc += r2[d] * W[2 * DD * DD + d * DD + c];
    }
    out[t] = acc;
}

__global__ void stats_kernel(const float* x, float* stats, int N) {
    int c = blockIdx.x;
    int tid = threadIdx.x;
    float s = 0.f, ss = 0.f;
    for (int r = tid; r < N; r += 1024) {
        float v = x[r * DD + c];
        s += v; ss += v * v;
    }
    __shared__ float shs[1024];
    __shared__ float shq[1024];
    shs[tid] = s; shq[tid] = ss;
    __syncthreads();
    for (int off = 512; off > 0; off >>= 1) {
        if (tid < off) { shs[tid] += shs[tid + off]; shq[tid] += shq[tid + off]; }
        __syncthreads();
    }
    if (tid == 0) { stats[c] = shs[0]; stats[DD + c] = shq[0]; }
}

// ===========================================================================

extern "C" void kernel_launch(void* const* d_in, const int* in_sizes, int n_in,
                              void* d_out, int out_size, void* d_ws, size_t ws_size,
                              hipStream_t stream) {
    const float* y   = (const float*)d_in[0];
    const int*   ei  = (const int*)d_in[1];
    const float* ew  = (const float*)d_in[2];
    const float* W1  = (const float*)d_in[3];
    const float* b1  = (const float*)d_in[4];
    const float* g1  = (const float*)d_in[5];
    const float* be1 = (const float*)d_in[6];
    const float* W2  = (const float*)d_in[7];
    const float* b2  = (const float*)d_in[8];
    const float* g2  = (const float*)d_in[9];
    const float* be2 = (const float*)d_in[10];
    float* out = (float*)d_out;

    const int N = in_sizes[0] / DD;      // 100000
    const int E = in_sizes[2];           // 1600000
    const int total = N * DD;

    const int* src = ei;
    const int* dst = ei + E;

    const int NBUK = (N + BKL - 1) / BKL;         // 782
    const int TOTC = NBUK * EBLK;                 // 200192
    const int TOTCP = (TOTC + 4) & ~3;            // pad -> perm2 8B-aligned
    const int EPB  = (E + EBLK - 1) / EBLK;       // 6250
    const int NB2  = (TOTC + 1023) / 1024;        // 196

    // ws layout:
    // st(128f) | h1(total f) | h2(total f)[=xb16/zb u16] | scanT(TOTCP i) |
    // perm2(E int2) | h1b(total u16)[part aliases]      (bsum/boff alias h1)
    float* st     = (float*)d_ws;
    float* h1     = st + 128;
    float* h2     = h1 + total;
    int*   scanT  = (int*)(h2 + total);
    int2*  perm2  = (int2*)(scanT + TOTCP);
    u16*   h1b    = (u16*)(perm2 + E);
    float* part   = (float*)h1b;                  // disjoint live ranges
    u16*   xb16   = (u16*)h2;                     // disjoint live ranges

    int*   bsum   = (int*)h1;                     // scan scratch (h1 dead then)
    int*   boff   = bsum + 256;

    const size_t tailBytes = ((size_t)total * 2 > (size_t)SB * 64 * 4)
                               ? (size_t)total * 2 : (size_t)SB * 64 * 4;
    const size_t need = ((size_t)128 + 2 * (size_t)total + TOTCP) * 4
                        + (size_t)E * 8 + tailBytes;
    const bool fast = (ws_size >= need) && (NBUK <= MAXBUK) && (N <= (1 << 20));

    const float invN = 1.0f / (float)N;
    dim3 blk(256);
    const int cgrid = (total + 255) / 256;
    const int fgrid = (TOTC + 255) / 256;
    const int zgrid = (2 * total + 255) / 256;
    const int pgrid = (E * DD + 255) / 256;
    const int vgrid = 1024;

    if (fast) {
        // ---- bucketed counting sort (shared by all 4 propagations) ----
        count_kernel<<<EBLK, blk, 0, stream>>>(dst, scanT, E, EPB, NBUK);
        scan_block_kernel<<<NB2, 1024, 0, stream>>>(scanT, scanT, bsum, TOTC);
        scan_sums256<<<1, 256, 0, stream>>>(bsum, boff, NB2);
        add_flat_kernel<<<fgrid, blk, 0, stream>>>(scanT, boff, TOTC);
        shard_kernel<<<EBLK, blk, 0, stream>>>(src, dst, ew, scanT, perm2, E, EPB, NBUK);

        // ---- layer 1 ----
        cvt_bf16_kernel<<<cgrid, blk, 0, stream>>>(y, xb16, total);
        prop_lds_kernel<true><<<NBUK, blk, 0, stream>>>(xb16, scanT, perm2, h1, h1b, N, E, NBUK);
        prop_lds_kernel<false><<<NBUK, blk, 0, stream>>>(h1b, scanT, perm2, h2, nullptr, N, E, NBUK);
        combine_v3<<<vgrid, blk, 0, stream>>>(y, h1, h2, W1, out, N);
        stats_part_kernel<<<SB, blk, 0, stream>>>(out, part, total);
        stats_final_kernel<<<1, 64, 0, stream>>>(part, st);
        bnrelu_kernel<true><<<cgrid, blk, 0, stream>>>(out, st, g1, be1, out, xb16, total, invN);

        // ---- layer 2 ----
        prop_lds_kernel<true><<<NBUK, blk, 0, stream>>>(xb16, scanT, perm2, h1, h1b, N, E, NBUK);
        prop_lds_kernel<false><<<NBUK, blk, 0, stream>>>(h1b, scanT, perm2, h2, nullptr, N, E, NBUK);
        combine_v3<<<vgrid, blk, 0, stream>>>(out, h1, h2, W2, out, N);
        stats_part_kernel<<<SB, blk, 0, stream>>>(out, part, total);
        stats_final_kernel<<<1, 64, 0, stream>>>(part, st + 64);
        bnrelu_kernel<false><<<cgrid, blk, 0, stream>>>(out, st + 64, g2, be2, out, nullptr, total, invN);
    } else {
        // ---- fallback: round-3 proven scatter path ----
        zero_kernel<<<zgrid, blk, 0, stream>>>(h1, 2 * total);
        prop_kernel<<<pgrid, blk, 0, stream>>>(y,  src, dst, ew, h1, E);
        prop_kernel<<<pgrid, blk, 0, stream>>>(h1, src, dst, ew, h2, E);
        combine_basic<<<cgrid, blk, 0, stream>>>(y, h1, h2, W1, b1, out, N);
        stats_kernel<<<32, 1024, 0, stream>>>(out, st, N);
        bnrelu_kernel<false><<<cgrid, blk, 0, stream>>>(out, st, g1, be1, out, nullptr, total, invN);

        zero_kernel<<<zgrid, blk, 0, stream>>>(h1, 2 * total);
        prop_kernel<<<pgrid, blk, 0, stream>>>(out, src, dst, ew, h1, E);
        prop_kernel<<<pgrid, blk, 0, stream>>>(h1,  src, dst, ew, h2, E);
        combine_basic<<<cgrid, blk, 0, stream>>>(out, h1, h2, W2, b2, out, N);
        stats_kernel<<<32, 1024, 0, stream>>>(out, st + 2 * DD, N);
        bnrelu_kernel<false><<<cgrid, blk, 0, stream>>>(out, st + 2 * DD, g2, be2, out, nullptr, total, invN);
    }
}

// Round 13
// 750.965 us; speedup vs baseline: 2.3462x; 2.3462x over previous
//
#include <hip/hip_runtime.h>

#define DD 32
#define NEG_SLOPE 0.01f
#define BN_EPS 1e-5f
#define SB 256          // stats partial blocks

typedef unsigned short u16;
typedef unsigned int u32;

__device__ __forceinline__ u16 f32_to_bf16(float f) {   // RNE
    u32 u = __float_as_uint(f);
    return (u16)((u + 0x7FFFu + ((u >> 16) & 1u)) >> 16);
}
__device__ __forceinline__ float bf16_to_f32(u16 b) {
    return __uint_as_float(((u32)b) << 16);
}

// ======================= helpers ===========================================

__global__ void zero_kernel(float* p, int n) {
    int i = blockIdx.x * blockDim.x + threadIdx.x;
    if (i < n) p[i] = 0.0f;
}
__global__ void zero_int_kernel(int* p, int n) {
    int i = blockIdx.x * blockDim.x + threadIdx.x;
    if (i < n) p[i] = 0;
}
__global__ void cvt_bf16_kernel(const float* __restrict__ x, u16* __restrict__ xb, int n) {
    int i = blockIdx.x * blockDim.x + threadIdx.x;
    if (i < n) xb[i] = f32_to_bf16(x[i]);
}

// ======================= CSR build (round-8 proven) ========================

__global__ void hist_kernel(const int* dst, int* deg, int E) {
    int e = blockIdx.x * blockDim.x + threadIdx.x;
    if (e < E) atomicAdd(&deg[dst[e]], 1);
}

__global__ void scan_block_kernel(const int* deg, int* pre, int* bsum, int N) {
    __shared__ int sh[1024];
    int tid = threadIdx.x;
    int i = blockIdx.x * 1024 + tid;
    int v = (i < N) ? deg[i] : 0;
    sh[tid] = v;
    __syncthreads();
    for (int off = 1; off < 1024; off <<= 1) {
        int t = (tid >= off) ? sh[tid - off] : 0;
        __syncthreads();
        sh[tid] += t;
        __syncthreads();
    }
    if (i < N) pre[i] = sh[tid] - v;              // exclusive
    if (tid == 1023) bsum[blockIdx.x] = sh[1023];
}

__global__ void scan_sums_kernel(const int* bsum, int* boff, int nb) {
    __shared__ int sh[128];
    int tid = threadIdx.x;
    int v = (tid < nb) ? bsum[tid] : 0;
    sh[tid] = v;
    __syncthreads();
    for (int off = 1; off < 128; off <<= 1) {
        int t = (tid >= off) ? sh[tid - off] : 0;
        __syncthreads();
        sh[tid] += t;
        __syncthreads();
    }
    if (tid < nb) boff[tid] = sh[tid] - v;        // exclusive
}

__global__ void add_off_kernel(int* rowptr, int* cursor, const int* boff, int N, int E) {
    int i = blockIdx.x * blockDim.x + threadIdx.x;
    if (i < N) {
        int v = rowptr[i] + boff[i >> 10];
        rowptr[i] = v;
        cursor[i] = v;
    }
    if (i == 0) rowptr[N] = E;
}

// one 8B packed store per edge: perm[p] = {src, bitcast(w)}
__global__ void fill_kernel(const int* src, const int* dst, const float* ew,
                            int* cursor, int2* perm, int E) {
    int e = blockIdx.x * blockDim.x + threadIdx.x;
    if (e >= E) return;
    int p = atomicAdd(&cursor[dst[e]], 1);
    int2 q;
    q.x = src[e];
    q.y = __float_as_int(ew[e]);
    perm[p] = q;
}

// ======================= gather v2: 64 lanes/node, 2 halves ================
// out[n][c] = sum_j w_j * xb[src_j][c]; halves interleave the edge list
// (stride 2), 2 indep accumulators per half, cross-half add via shfl_xor(32).
template <bool EMIT>
__global__ void gather2_kernel(const u16* __restrict__ xb,
                               const int* __restrict__ rowptr,
                               const int2* __restrict__ perm,
                               float* __restrict__ out,
                               u16* __restrict__ outb, int N) {
    int t = blockIdx.x * blockDim.x + threadIdx.x;
    int n = t >> 6;                               // 64 lanes per node
    if (n >= N) return;
    int lane = threadIdx.x & 63;
    int half = lane >> 5;
    int c = lane & 31;
    int b = rowptr[n], e = rowptr[n + 1];
    float a0 = 0.f, a1 = 0.f;
    int j = b + half;                             // this half's interleaved list
    for (; j + 2 < e; j += 4) {                   // 2 edges in flight per half
        int2 qa = perm[j];
        int2 qb = perm[j + 2];
        a0 += __int_as_float(qa.y) * bf16_to_f32(xb[qa.x * DD + c]);
        a1 += __int_as_float(qb.y) * bf16_to_f32(xb[qb.x * DD + c]);
    }
    if (j < e) {
        int2 q = perm[j];
        a0 += __int_as_float(q.y) * bf16_to_f32(xb[q.x * DD + c]);
    }
    float acc = a0 + a1;
    acc += __shfl_xor(acc, 32);                   // combine halves (wave64)
    if (half == 0) {
        out[n * DD + c] = acc;
        if (EMIT) outb[n * DD + c] = f32_to_bf16(acc);
    }
}

// ======================= combine v3 (registers; no launch_bounds) ==========
// out[n][c] = sum_d x0*W0[d][c] + x1*W1[d][c] + x2*W2[d][c]
// (bias dropped: BN mean-subtraction cancels per-column constants exactly)
// In-place on x0 safe: a thread's row loads all precede its single store.
__global__ void combine_v3(const float* x0, const float* __restrict__ x1,
                           const float* __restrict__ x2, const float* __restrict__ W,
                           float* out, int N) {
    int c = threadIdx.x & 31;
    float w0[DD], w1[DD], w2[DD];
#pragma unroll
    for (int d = 0; d < DD; ++d) {
        w0[d] = W[d * DD + c];
        w1[d] = W[DD * DD + d * DD + c];
        w2[d] = W[2 * DD * DD + d * DD + c];
    }
    int group   = (blockIdx.x * blockDim.x + threadIdx.x) >> 5;
    int ngroups = (gridDim.x * blockDim.x) >> 5;
    for (int n = group; n < N; n += ngroups) {
        const float4* r0 = reinterpret_cast<const float4*>(x0 + (size_t)n * DD);
        const float4* r1 = reinterpret_cast<const float4*>(x1 + (size_t)n * DD);
        const float4* r2 = reinterpret_cast<const float4*>(x2 + (size_t)n * DD);
        float acc = 0.f;
#pragma unroll
        for (int q = 0; q < DD / 4; ++q) {
            float4 v0 = r0[q];
            float4 v1 = r1[q];
            float4 v2 = r2[q];
            acc += v0.x * w0[4*q] + v0.y * w0[4*q+1] + v0.z * w0[4*q+2] + v0.w * w0[4*q+3];
            acc += v1.x * w1[4*q] + v1.y * w1[4*q+1] + v1.z * w1[4*q+2] + v1.w * w1[4*q+3];
            acc += v2.x * w2[4*q] + v2.y * w2[4*q+1] + v2.z * w2[4*q+2] + v2.w * w2[4*q+3];
        }
        out[(size_t)n * DD + c] = acc;
    }
}

// ======================= stats + bnrelu (proven) ===========================

__global__ void stats_part_kernel(const float* x, float* part, int total) {
    int tid = threadIdx.x;
    int idx = blockIdx.x * 256 + tid;
    const int stride = SB * 256;
    float s = 0.f, ss = 0.f;
    for (int i = idx; i < total; i += stride) { float v = x[i]; s += v; ss += v * v; }
    __shared__ float sh[2][8][DD];
    sh[0][tid >> 5][tid & 31] = s;
    sh[1][tid >> 5][tid & 31] = ss;
    __syncthreads();
    if (tid < DD) {
        float ts = 0.f, tss = 0.f;
        for (int g = 0; g < 8; ++g) { ts += sh[0][g][tid]; tss += sh[1][g][tid]; }
        part[blockIdx.x * 64 + tid] = ts;
        part[blockIdx.x * 64 + DD + tid] = tss;
    }
}

__global__ void stats_final_kernel(const float* part, float* st) {
    int tid = threadIdx.x;                        // 64 threads
    if (tid < 64) {
        float a = 0.f;
        for (int b = 0; b < SB; ++b) a += part[b * 64 + tid];
        st[tid] = a;
    }
}

template <bool EMIT>
__global__ void bnrelu_kernel(const float* x, const float* stats,
                              const float* gamma, const float* beta,
                              float* out, u16* outb, int total, float invN) {
    int i = blockIdx.x * blockDim.x + threadIdx.x;
    if (i >= total) return;
    int c = i & 31;
    float m   = stats[c] * invN;
    float msq = stats[DD + c] * invN;
    float var = msq - m * m;
    float inv = 1.0f / sqrtf(var + BN_EPS);
    float v = (x[i] - m) * inv * gamma[c] + beta[c];
    v = v >= 0.f ? v : NEG_SLOPE * v;
    out[i] = v;
    if (EMIT) outb[i] = f32_to_bf16(v);
}

// ======================= fallback path (round-3, proven) ===================

__global__ void prop_kernel(const float* x, const int* src, const int* dst,
                            const float* ew, float* out, int E) {
    int t = blockIdx.x * blockDim.x + threadIdx.x;
    int e = t >> 5;
    if (e >= E) return;
    int c = t & 31;
    float v = ew[e] * x[src[e] * DD + c];
    atomicAdd(&out[dst[e] * DD + c], v);
}

__global__ void combine_basic(const float* x0, const float* x1, const float* x2,
                              const float* W, const float* bias,
                              float* out, int N) {
    int t = blockIdx.x * blockDim.x + threadIdx.x;
    int n = t >> 5;
    if (n >= N) return;
    int c = t & 31;
    const float* r0 = x0 + n * DD;
    const float* r1 = x1 + n * DD;
    const float* r2 = x2 + n * DD;
    float acc = bias[c];
    for (int d = 0; d < DD; ++d) {
        acc += r0[d] * W[d * DD + c];
        acc += r1[d] * W[DD * DD + d * DD + c];
        acc += r2[d] * W[2 * DD * DD + d * DD + c];
    }
    out[t] = acc;
}

__global__ void stats_kernel(const float* x, float* stats, int N) {
    int c = blockIdx.x;
    int tid = threadIdx.x;
    float s = 0.f, ss = 0.f;
    for (int r = tid; r < N; r += 1024) {
        float v = x[r * DD + c];
        s += v; ss += v * v;
    }
    __shared__ float shs[1024];
    __shared__ float shq[1024];
    shs[tid] = s; shq[tid] = ss;
    __syncthreads();
    for (int off = 512; off > 0; off >>= 1) {
        if (tid < off) { shs[tid] += shs[tid + off]; shq[tid] += shq[tid + off]; }
        __syncthreads();
    }
    if (tid == 0) { stats[c] = shs[0]; stats[DD + c] = shq[0]; }
}

// ===========================================================================

extern "C" void kernel_launch(void* const* d_in, const int* in_sizes, int n_in,
                              void* d_out, int out_size, void* d_ws, size_t ws_size,
                              hipStream_t stream) {
    const float* y   = (const float*)d_in[0];
    const int*   ei  = (const int*)d_in[1];
    const float* ew  = (const float*)d_in[2];
    const float* W1  = (const float*)d_in[3];
    const float* b1  = (const float*)d_in[4];
    const float* g1  = (const float*)d_in[5];
    const float* be1 = (const float*)d_in[6];
    const float* W2  = (const float*)d_in[7];
    const float* b2  = (const float*)d_in[8];
    const float* g2  = (const float*)d_in[9];
    const float* be2 = (const float*)d_in[10];
    float* out = (float*)d_out;

    const int N = in_sizes[0] / DD;     // 100000
    const int E = in_sizes[2];          // 1600000
    const int total = N * DD;

    const int* src = ei;
    const int* dst = ei + E;

    // persistent ws layout; RP multiple of 4 so perm (int2) is 16B-aligned
    const int RP = (N + 4) & ~3;                 // 100004
    float* st     = (float*)d_ws;                // 128 f
    float* h1     = st + 128;                    // total f
    float* h2     = h1 + total;                  // total f
    int*   rowptr = (int*)(h2 + total);          // RP i (rowptr[N]=E used)
    int2*  perm   = (int2*)(rowptr + RP);        // E int2
    u16*   h1b    = (u16*)(perm + E);            // total u16 (part aliases)
    float* part   = (float*)h1b;                 // disjoint live ranges
    u16*   xb16   = (u16*)h2;                    // disjoint live ranges

    const size_t tailBytes = ((size_t)total * 2 > (size_t)SB * 64 * 4)
                               ? (size_t)total * 2 : (size_t)SB * 64 * 4;
    const size_t need_bf16 = ((size_t)128 + 2 * (size_t)total + RP) * 4
                             + (size_t)E * 8 + tailBytes;
    const bool use_bf16 = ws_size >= need_bf16;

    // CSR-build scratch aliased into h1/h2 (dead before propagation starts)
    int* cursor = (int*)h1;                      // N i
    int* bsum   = (int*)h1 + N;                  // ≤128 i
    int* boff   = bsum + 128;                    // ≤128 i
    int* deg    = (int*)h2;                      // N i

    const int NB = (N + 1023) / 1024;            // 98
    const float invN = 1.0f / (float)N;
    dim3 blk(256);
    const int ngrid = (N + 255) / 256;
    const int egrid = (E + 255) / 256;
    const int cgrid = (total + 255) / 256;
    const int ggrid = (2 * total + 255) / 256;   // 64 lanes per node
    const int zgrid = (2 * total + 255) / 256;
    const int pgrid = (E * DD + 255) / 256;
    const int vgrid = 1024;

    if (use_bf16) {
        // ---- build CSR by destination ----
        zero_int_kernel<<<ngrid, blk, 0, stream>>>(deg, N);
        hist_kernel<<<egrid, blk, 0, stream>>>(dst, deg, E);
        scan_block_kernel<<<NB, 1024, 0, stream>>>(deg, rowptr, bsum, N);
        scan_sums_kernel<<<1, 128, 0, stream>>>(bsum, boff, NB);
        add_off_kernel<<<ngrid, blk, 0, stream>>>(rowptr, cursor, boff, N, E);
        fill_kernel<<<egrid, blk, 0, stream>>>(src, dst, ew, cursor, perm, E);

        // ---- layer 1 ----
        cvt_bf16_kernel<<<cgrid, blk, 0, stream>>>(y, xb16, total);
        gather2_kernel<true><<<ggrid, blk, 0, stream>>>(xb16, rowptr, perm, h1, h1b, N);
        gather2_kernel<false><<<ggrid, blk, 0, stream>>>(h1b, rowptr, perm, h2, nullptr, N);
        combine_v3<<<vgrid, blk, 0, stream>>>(y, h1, h2, W1, out, N);
        stats_part_kernel<<<SB, blk, 0, stream>>>(out, part, total);
        stats_final_kernel<<<1, 64, 0, stream>>>(part, st);
        bnrelu_kernel<true><<<cgrid, blk, 0, stream>>>(out, st, g1, be1, out, xb16, total, invN);

        // ---- layer 2 ----
        gather2_kernel<true><<<ggrid, blk, 0, stream>>>(xb16, rowptr, perm, h1, h1b, N);
        gather2_kernel<false><<<ggrid, blk, 0, stream>>>(h1b, rowptr, perm, h2, nullptr, N);
        combine_v3<<<vgrid, blk, 0, stream>>>(out, h1, h2, W2, out, N);
        stats_part_kernel<<<SB, blk, 0, stream>>>(out, part, total);
        stats_final_kernel<<<1, 64, 0, stream>>>(part, st + 64);
        bnrelu_kernel<false><<<cgrid, blk, 0, stream>>>(out, st + 64, g2, be2, out, nullptr, total, invN);
    } else {
        // ---- fallback: round-3 proven scatter path ----
        zero_kernel<<<zgrid, blk, 0, stream>>>(h1, 2 * total);
        prop_kernel<<<pgrid, blk, 0, stream>>>(y,  src, dst, ew, h1, E);
        prop_kernel<<<pgrid, blk, 0, stream>>>(h1, src, dst, ew, h2, E);
        combine_basic<<<cgrid, blk, 0, stream>>>(y, h1, h2, W1, b1, out, N);
        stats_kernel<<<32, 1024, 0, stream>>>(out, st, N);
        bnrelu_kernel<false><<<cgrid, blk, 0, stream>>>(out, st, g1, be1, out, nullptr, total, invN);

        zero_kernel<<<zgrid, blk, 0, stream>>>(h1, 2 * total);
        prop_kernel<<<pgrid, blk, 0, stream>>>(out, src, dst, ew, h1, E);
        prop_kernel<<<pgrid, blk, 0, stream>>>(h1,  src, dst, ew, h2, E);
        combine_basic<<<cgrid, blk, 0, stream>>>(out, h1, h2, W2, b2, out, N);
        stats_kernel<<<32, 1024, 0, stream>>>(out, st + 2 * DD, N);
        bnrelu_kernel<false><<<cgrid, blk, 0, stream>>>(out, st + 2 * DD, g2, be2, out, nullptr, total, invN);
    }
}

// Round 14
// 660.499 us; speedup vs baseline: 2.6675x; 1.1370x over previous
//
#include <hip/hip_runtime.h>

#define DD 32
#define NEG_SLOPE 0.01f
#define BN_EPS 1e-5f
#define SB 256          // stats partial blocks
#define BKL 128         // nodes per dst-bucket
#define EBLK 256        // edge blocks for counting sort
#define MAXBUK 800      // LDS counter capacity

typedef unsigned short u16;
typedef unsigned int u32;

__device__ __forceinline__ u16 f32_to_bf16(float f) {   // RNE
    u32 u = __float_as_uint(f);
    return (u16)((u + 0x7FFFu + ((u >> 16) & 1u)) >> 16);
}
__device__ __forceinline__ float bf16_to_f32(u16 b) {
    return __uint_as_float(((u32)b) << 16);
}

// ======================= helpers ===========================================

__global__ void zero_kernel(float* p, int n) {
    int i = blockIdx.x * blockDim.x + threadIdx.x;
    if (i < n) p[i] = 0.0f;
}
__global__ void zero_int_kernel(int* p, int n) {
    int i = blockIdx.x * blockDim.x + threadIdx.x;
    if (i < n) p[i] = 0;
}
__global__ void cvt_bf16_kernel(const float* __restrict__ x, u16* __restrict__ xb, int n) {
    int i = blockIdx.x * blockDim.x + threadIdx.x;
    if (i < n) xb[i] = f32_to_bf16(x[i]);
}

// ======================= bucket counting sort (r10-proven) =================
// Pass A: per-(edge-block,bucket) counts, bucket-major: countsT[buk*EBLK+eb]
__global__ void count_kernel(const int* __restrict__ dst, int* __restrict__ countsT,
                             int E, int EPB, int NBUK) {
    __shared__ int cnt[MAXBUK];
    int eb = blockIdx.x;
    for (int i = threadIdx.x; i < NBUK; i += blockDim.x) cnt[i] = 0;
    __syncthreads();
    int lo = eb * EPB;
    int hi = lo + EPB; if (hi > E) hi = E;
    for (int e = lo + threadIdx.x; e < hi; e += blockDim.x)
        atomicAdd(&cnt[dst[e] >> 7], 1);          // BKL=128
    __syncthreads();
    for (int i = threadIdx.x; i < NBUK; i += blockDim.x)
        countsT[i * EBLK + eb] = cnt[i];
}

// generic block scan (used for both bucket-count scan and node-degree scan)
__global__ void scan_block_kernel(const int* deg, int* pre, int* bsum, int N) {
    __shared__ int sh[1024];
    int tid = threadIdx.x;
    int i = blockIdx.x * 1024 + tid;
    int v = (i < N) ? deg[i] : 0;
    sh[tid] = v;
    __syncthreads();
    for (int off = 1; off < 1024; off <<= 1) {
        int t = (tid >= off) ? sh[tid - off] : 0;
        __syncthreads();
        sh[tid] += t;
        __syncthreads();
    }
    if (i < N) pre[i] = sh[tid] - v;              // exclusive
    if (tid == 1023) bsum[blockIdx.x] = sh[1023];
}

__global__ void scan_sums256(const int* bsum, int* boff, int nb) {
    __shared__ int sh[256];
    int tid = threadIdx.x;
    int v = (tid < nb) ? bsum[tid] : 0;
    sh[tid] = v;
    __syncthreads();
    for (int off = 1; off < 256; off <<= 1) {
        int t = (tid >= off) ? sh[tid - off] : 0;
        __syncthreads();
        sh[tid] += t;
        __syncthreads();
    }
    if (tid < nb) boff[tid] = sh[tid] - v;        // exclusive
}

__global__ void add_flat_kernel(int* a, const int* boff, int n) {
    int i = blockIdx.x * blockDim.x + threadIdx.x;
    if (i < n) a[i] += boff[i >> 10];
}

// Pass B: scatter into per-(block,bucket) contiguous shards (write-local)
// pack: q.x = (dst&127)<<20 | src (needs N <= 2^20), q.y = bits(w)
__global__ void shard_kernel(const int* __restrict__ src, const int* __restrict__ dst,
                             const float* __restrict__ ew, const int* __restrict__ scanT,
                             int2* __restrict__ perm2, int E, int EPB, int NBUK) {
    __shared__ int cur[MAXBUK];
    int eb = blockIdx.x;
    for (int i = threadIdx.x; i < NBUK; i += blockDim.x)
        cur[i] = scanT[i * EBLK + eb];
    __syncthreads();
    int lo = eb * EPB;
    int hi = lo + EPB; if (hi > E) hi = E;
    for (int e = lo + threadIdx.x; e < hi; e += blockDim.x) {
        int d = dst[e];
        int slot = atomicAdd(&cur[d >> 7], 1);
        int2 q;
        q.x = ((d & (BKL - 1)) << 20) | src[e];
        q.y = __float_as_int(ew[e]);
        perm2[slot] = q;
    }
}

// Pass C: bucket-local reorder into node-ordered CSR perm (writes stay in a
// ~16KB L2-resident window per block; no line amplification)
__global__ void reorder_kernel(const int2* __restrict__ perm2,
                               const int* __restrict__ scanT,
                               int* __restrict__ cursor,
                               int2* __restrict__ perm, int E, int NBUK) {
    int b = blockIdx.x;
    int lo = scanT[b * EBLK];
    int hi = (b + 1 < NBUK) ? scanT[(b + 1) * EBLK] : E;
    int base = b * BKL;
    for (int j = lo + threadIdx.x; j < hi; j += blockDim.x) {
        int2 q = perm2[j];
        int d = base + (q.x >> 20);
        int slot = atomicAdd(&cursor[d], 1);
        int2 o;
        o.x = q.x & 0xFFFFF;
        o.y = q.y;
        perm[slot] = o;
    }
}

// ======================= node-level rowptr =================================

__global__ void hist_kernel(const int* dst, int* deg, int E) {
    int e = blockIdx.x * blockDim.x + threadIdx.x;
    if (e < E) atomicAdd(&deg[dst[e]], 1);
}

__global__ void add_off_kernel(int* rowptr, int* cursor, const int* boff, int N, int E) {
    int i = blockIdx.x * blockDim.x + threadIdx.x;
    if (i < N) {
        int v = rowptr[i] + boff[i >> 10];
        rowptr[i] = v;
        cursor[i] = v;
    }
    if (i == 0) rowptr[N] = E;
}

// ======================= gather: 64 lanes/node, 2 halves (r13) =============
template <bool EMIT>
__global__ void gather2_kernel(const u16* __restrict__ xb,
                               const int* __restrict__ rowptr,
                               const int2* __restrict__ perm,
                               float* __restrict__ out,
                               u16* __restrict__ outb, int N) {
    int t = blockIdx.x * blockDim.x + threadIdx.x;
    int n = t >> 6;                               // 64 lanes per node
    if (n >= N) return;
    int lane = threadIdx.x & 63;
    int half = lane >> 5;
    int c = lane & 31;
    int b = rowptr[n], e = rowptr[n + 1];
    float a0 = 0.f, a1 = 0.f;
    int j = b + half;
    for (; j + 2 < e; j += 4) {
        int2 qa = perm[j];
        int2 qb = perm[j + 2];
        a0 += __int_as_float(qa.y) * bf16_to_f32(xb[qa.x * DD + c]);
        a1 += __int_as_float(qb.y) * bf16_to_f32(xb[qb.x * DD + c]);
    }
    if (j < e) {
        int2 q = perm[j];
        a0 += __int_as_float(q.y) * bf16_to_f32(xb[q.x * DD + c]);
    }
    float acc = a0 + a1;
    acc += __shfl_xor(acc, 32);
    if (half == 0) {
        out[n * DD + c] = acc;
        if (EMIT) outb[n * DD + c] = f32_to_bf16(acc);
    }
}

// ======================= combine v3b: registers, (256,2) -> 128 VGPR =======
// out[n][c] = sum_d x0*W0[d][c] + x1*W1[d][c] + x2*W2[d][c]
// (bias dropped: BN mean-subtraction cancels per-column constants exactly)
// 96 weights + ~24 working regs ~= 120 < 128: no spill at 2 waves/SIMD.
// In-place on x0 safe: a thread's row loads all precede its single store.
__global__ __launch_bounds__(256, 2)
void combine_v3b(const float* x0, const float* __restrict__ x1,
                 const float* __restrict__ x2, const float* __restrict__ W,
                 float* out, int N) {
    int c = threadIdx.x & 31;
    float w0[DD], w1[DD], w2[DD];
#pragma unroll
    for (int d = 0; d < DD; ++d) {
        w0[d] = W[d * DD + c];
        w1[d] = W[DD * DD + d * DD + c];
        w2[d] = W[2 * DD * DD + d * DD + c];
    }
    int group   = (blockIdx.x * blockDim.x + threadIdx.x) >> 5;
    int ngroups = (gridDim.x * blockDim.x) >> 5;
    for (int n = group; n < N; n += ngroups) {
        const float4* r0 = reinterpret_cast<const float4*>(x0 + (size_t)n * DD);
        const float4* r1 = reinterpret_cast<const float4*>(x1 + (size_t)n * DD);
        const float4* r2 = reinterpret_cast<const float4*>(x2 + (size_t)n * DD);
        float acc = 0.f;
#pragma unroll
        for (int q = 0; q < DD / 4; ++q) {
            float4 v0 = r0[q];
            float4 v1 = r1[q];
            float4 v2 = r2[q];
            acc += v0.x * w0[4*q] + v0.y * w0[4*q+1] + v0.z * w0[4*q+2] + v0.w * w0[4*q+3];
            acc += v1.x * w1[4*q] + v1.y * w1[4*q+1] + v1.z * w1[4*q+2] + v1.w * w1[4*q+3];
            acc += v2.x * w2[4*q] + v2.y * w2[4*q+1] + v2.z * w2[4*q+2] + v2.w * w2[4*q+3];
        }
        out[(size_t)n * DD + c] = acc;
    }
}

// ======================= stats + bnrelu (proven) ===========================

__global__ void stats_part_kernel(const float* x, float* part, int total) {
    int tid = threadIdx.x;
    int idx = blockIdx.x * 256 + tid;
    const int stride = SB * 256;
    float s = 0.f, ss = 0.f;
    for (int i = idx; i < total; i += stride) { float v = x[i]; s += v; ss += v * v; }
    __shared__ float sh[2][8][DD];
    sh[0][tid >> 5][tid & 31] = s;
    sh[1][tid >> 5][tid & 31] = ss;
    __syncthreads();
    if (tid < DD) {
        float ts = 0.f, tss = 0.f;
        for (int g = 0; g < 8; ++g) { ts += sh[0][g][tid]; tss += sh[1][g][tid]; }
        part[blockIdx.x * 64 + tid] = ts;
        part[blockIdx.x * 64 + DD + tid] = tss;
    }
}

__global__ void stats_final_kernel(const float* part, float* st) {
    int tid = threadIdx.x;                        // 64 threads
    if (tid < 64) {
        float a = 0.f;
        for (int b = 0; b < SB; ++b) a += part[b * 64 + tid];
        st[tid] = a;
    }
}

template <bool EMIT>
__global__ void bnrelu_kernel(const float* x, const float* stats,
                              const float* gamma, const float* beta,
                              float* out, u16* outb, int total, float invN) {
    int i = blockIdx.x * blockDim.x + threadIdx.x;
    if (i >= total) return;
    int c = i & 31;
    float m   = stats[c] * invN;
    float msq = stats[DD + c] * invN;
    float var = msq - m * m;
    float inv = 1.0f / sqrtf(var + BN_EPS);
    float v = (x[i] - m) * inv * gamma[c] + beta[c];
    v = v >= 0.f ? v : NEG_SLOPE * v;
    out[i] = v;
    if (EMIT) outb[i] = f32_to_bf16(v);
}

// ======================= fallback path (round-3, proven) ===================

__global__ void prop_kernel(const float* x, const int* src, const int* dst,
                            const float* ew, float* out, int E) {
    int t = blockIdx.x * blockDim.x + threadIdx.x;
    int e = t >> 5;
    if (e >= E) return;
    int c = t & 31;
    float v = ew[e] * x[src[e] * DD + c];
    atomicAdd(&out[dst[e] * DD + c], v);
}

__global__ void combine_basic(const float* x0, const float* x1, const float* x2,
                              const float* W, const float* bias,
                              float* out, int N) {
    int t = blockIdx.x * blockDim.x + threadIdx.x;
    int n = t >> 5;
    if (n >= N) return;
    int c = t & 31;
    const float* r0 = x0 + n * DD;
    const float* r1 = x1 + n * DD;
    const float* r2 = x2 + n * DD;
    float acc = bias[c];
    for (int d = 0; d < DD; ++d) {
        acc += r0[d] * W[d * DD + c];
        acc += r1[d] * W[DD * DD + d * DD + c];
        acc += r2[d] * W[2 * DD * DD + d * DD + c];
    }
    out[t] = acc;
}

__global__ void stats_kernel(const float* x, float* stats, int N) {
    int c = blockIdx.x;
    int tid = threadIdx.x;
    float s = 0.f, ss = 0.f;
    for (int r = tid; r < N; r += 1024) {
        float v = x[r * DD + c];
        s += v; ss += v * v;
    }
    __shared__ float shs[1024];
    __shared__ float shq[1024];
    shs[tid] = s; shq[tid] = ss;
    __syncthreads();
    for (int off = 512; off > 0; off >>= 1) {
        if (tid < off) { shs[tid] += shs[tid + off]; shq[tid] += shq[tid + off]; }
        __syncthreads();
    }
    if (tid == 0) { stats[c] = shs[0]; stats[DD + c] = shq[0]; }
}

// ===========================================================================

extern "C" void kernel_launch(void* const* d_in, const int* in_sizes, int n_in,
                              void* d_out, int out_size, void* d_ws, size_t ws_size,
                              hipStream_t stream) {
    const float* y   = (const float*)d_in[0];
    const int*   ei  = (const int*)d_in[1];
    const float* ew  = (const float*)d_in[2];
    const float* W1  = (const float*)d_in[3];
    const float* b1  = (const float*)d_in[4];
    const float* g1  = (const float*)d_in[5];
    const float* be1 = (const float*)d_in[6];
    const float* W2  = (const float*)d_in[7];
    const float* b2  = (const float*)d_in[8];
    const float* g2  = (const float*)d_in[9];
    const float* be2 = (const float*)d_in[10];
    float* out = (float*)d_out;

    const int N = in_sizes[0] / DD;      // 100000
    const int E = in_sizes[2];           // 1600000
    const int total = N * DD;

    const int* src = ei;
    const int* dst = ei + E;

    const int NBUK = (N + BKL - 1) / BKL;         // 782
    const int TOTC = NBUK * EBLK;                 // 200192
    const int EPB  = (E + EBLK - 1) / EBLK;       // 6250
    const int NB2  = (TOTC + 1023) / 1024;        // 196
    const int NB   = (N + 1023) / 1024;           // 98

    // ws layout; RP multiple of 4 so perm stays 16B-aligned
    const int RP = (N + 4) & ~3;                  // 100004
    float* st     = (float*)d_ws;                 // 128 f
    float* h1     = st + 128;                     // total f
    float* h2     = h1 + total;                   // total f
    int*   rowptr = (int*)(h2 + total);           // RP i
    int2*  perm   = (int2*)(rowptr + RP);         // E int2 (node-ordered CSR)
    char*  tail   = (char*)(perm + E);
    u16*   h1b    = (u16*)tail;                   // total u16 (gather phase)
    float* part   = (float*)tail;                 // SB*64 f (stats phase)
    int*   scanT  = (int*)tail;                   // TOTC i (build phase)
    // build-phase aliases:
    int2*  perm2  = (int2*)h1;                    // E int2 == total f exactly
    u16*   xb16   = (u16*)h2;                     // bf16 rows (after build)
    int*   deg    = (int*)h2;                     // N i
    int*   cursor = deg + N;                      // N i
    int*   bsum   = deg + 2 * N;                  // 256 i
    int*   boff   = bsum + 256;                   // 256 i

    size_t tailBytes = (size_t)total * 2;
    if ((size_t)SB * 64 * 4 > tailBytes) tailBytes = (size_t)SB * 64 * 4;
    if ((size_t)TOTC * 4 > tailBytes)    tailBytes = (size_t)TOTC * 4;
    const size_t need = ((size_t)128 + 2 * (size_t)total + RP + 2 * (size_t)E) * 4 + tailBytes;
    const bool fast = (ws_size >= need) && (NBUK <= MAXBUK) && (N <= (1 << 20));

    const float invN = 1.0f / (float)N;
    dim3 blk(256);
    const int ngrid = (N + 255) / 256;
    const int egrid = (E + 255) / 256;
    const int cgrid = (total + 255) / 256;
    const int ggrid = (2 * total + 255) / 256;    // 64 lanes per node
    const int fgrid = (TOTC + 255) / 256;
    const int zgrid = (2 * total + 255) / 256;
    const int pgrid = (E * DD + 255) / 256;
    const int vgrid = 1024;

    if (fast) {
        // ---- bucket counting sort: count -> scan -> shard (write-local) ----
        count_kernel<<<EBLK, blk, 0, stream>>>(dst, scanT, E, EPB, NBUK);
        scan_block_kernel<<<NB2, 1024, 0, stream>>>(scanT, scanT, bsum, TOTC);
        scan_sums256<<<1, 256, 0, stream>>>(bsum, boff, NB2);
        add_flat_kernel<<<fgrid, blk, 0, stream>>>(scanT, boff, TOTC);
        shard_kernel<<<EBLK, blk, 0, stream>>>(src, dst, ew, scanT, perm2, E, EPB, NBUK);

        // ---- node-level rowptr + cursor ----
        zero_int_kernel<<<ngrid, blk, 0, stream>>>(deg, N);
        hist_kernel<<<egrid, blk, 0, stream>>>(dst, deg, E);
        scan_block_kernel<<<NB, 1024, 0, stream>>>(deg, rowptr, bsum, N);
        scan_sums256<<<1, 256, 0, stream>>>(bsum, boff, NB);
        add_off_kernel<<<ngrid, blk, 0, stream>>>(rowptr, cursor, boff, N, E);

        // ---- bucket-local reorder into node-ordered perm ----
        reorder_kernel<<<NBUK, blk, 0, stream>>>(perm2, scanT, cursor, perm, E, NBUK);

        // ---- layer 1 ----
        cvt_bf16_kernel<<<cgrid, blk, 0, stream>>>(y, xb16, total);   // overwrites deg/cursor (dead)
        gather2_kernel<true><<<ggrid, blk, 0, stream>>>(xb16, rowptr, perm, h1, h1b, N);  // h1 over perm2 (dead), h1b over scanT (dead)
        gather2_kernel<false><<<ggrid, blk, 0, stream>>>(h1b, rowptr, perm, h2, nullptr, N);
        combine_v3b<<<vgrid, blk, 0, stream>>>(y, h1, h2, W1, out, N);
        stats_part_kernel<<<SB, blk, 0, stream>>>(out, part, total);
        stats_final_kernel<<<1, 64, 0, stream>>>(part, st);
        bnrelu_kernel<true><<<cgrid, blk, 0, stream>>>(out, st, g1, be1, out, xb16, total, invN);

        // ---- layer 2 ----
        gather2_kernel<true><<<ggrid, blk, 0, stream>>>(xb16, rowptr, perm, h1, h1b, N);
        gather2_kernel<false><<<ggrid, blk, 0, stream>>>(h1b, rowptr, perm, h2, nullptr, N);
        combine_v3b<<<vgrid, blk, 0, stream>>>(out, h1, h2, W2, out, N);
        stats_part_kernel<<<SB, blk, 0, stream>>>(out, part, total);
        stats_final_kernel<<<1, 64, 0, stream>>>(part, st + 64);
        bnrelu_kernel<false><<<cgrid, blk, 0, stream>>>(out, st + 64, g2, be2, out, nullptr, total, invN);
    } else {
        // ---- fallback: round-3 proven scatter path ----
        zero_kernel<<<zgrid, blk, 0, stream>>>(h1, 2 * total);
        prop_kernel<<<pgrid, blk, 0, stream>>>(y,  src, dst, ew, h1, E);
        prop_kernel<<<pgrid, blk, 0, stream>>>(h1, src, dst, ew, h2, E);
        combine_basic<<<cgrid, blk, 0, stream>>>(y, h1, h2, W1, b1, out, N);
        stats_kernel<<<32, 1024, 0, stream>>>(out, st, N);
        bnrelu_kernel<false><<<cgrid, blk, 0, stream>>>(out, st, g1, be1, out, nullptr, total, invN);

        zero_kernel<<<zgrid, blk, 0, stream>>>(h1, 2 * total);
        prop_kernel<<<pgrid, blk, 0, stream>>>(out, src, dst, ew, h1, E);
        prop_kernel<<<pgrid, blk, 0, stream>>>(h1,  src, dst, ew, h2, E);
        combine_basic<<<cgrid, blk, 0, stream>>>(out, h1, h2, W2, b2, out, N);
        stats_kernel<<<32, 1024, 0, stream>>>(out, st + 2 * DD, N);
        bnrelu_kernel<false><<<cgrid, blk, 0, stream>>>(out, st + 2 * DD, g2, be2, out, nullptr, total, invN);
    }
}

// Round 16
// 630.477 us; speedup vs baseline: 2.7945x; 1.0476x over previous
//
#include <hip/hip_runtime.h>

#define DD 32
#define NEG_SLOPE 0.01f
#define BN_EPS 1e-5f
#define SB 256          // stats partial blocks
#define BKL 128         // nodes per dst-bucket
#define EBLK 256        // edge blocks for counting sort
#define MAXBUK 800      // LDS counter capacity

typedef unsigned short u16;
typedef unsigned int u32;

__device__ __forceinline__ u16 f32_to_bf16(float f) {   // RNE
    u32 u = __float_as_uint(f);
    return (u16)((u + 0x7FFFu + ((u >> 16) & 1u)) >> 16);
}
__device__ __forceinline__ float bf16_to_f32(u16 b) {
    return __uint_as_float(((u32)b) << 16);
}

// ======================= helpers ===========================================

__global__ void zero_kernel(float* p, int n) {
    int i = blockIdx.x * blockDim.x + threadIdx.x;
    if (i < n) p[i] = 0.0f;
}
__global__ void zero_int_kernel(int* p, int n) {
    int i = blockIdx.x * blockDim.x + threadIdx.x;
    if (i < n) p[i] = 0;
}
__global__ void cvt_bf16_kernel(const float* __restrict__ x, u16* __restrict__ xb, int n) {
    int i = blockIdx.x * blockDim.x + threadIdx.x;
    if (i < n) xb[i] = f32_to_bf16(x[i]);
}

// ======================= bucket counting sort (r10/r14 proven) =============

__global__ void count_kernel(const int* __restrict__ dst, int* __restrict__ countsT,
                             int E, int EPB, int NBUK) {
    __shared__ int cnt[MAXBUK];
    int eb = blockIdx.x;
    for (int i = threadIdx.x; i < NBUK; i += blockDim.x) cnt[i] = 0;
    __syncthreads();
    int lo = eb * EPB;
    int hi = lo + EPB; if (hi > E) hi = E;
    for (int e = lo + threadIdx.x; e < hi; e += blockDim.x)
        atomicAdd(&cnt[dst[e] >> 7], 1);          // BKL=128
    __syncthreads();
    for (int i = threadIdx.x; i < NBUK; i += blockDim.x)
        countsT[i * EBLK + eb] = cnt[i];
}

__global__ void scan_block_kernel(const int* deg, int* pre, int* bsum, int N) {
    __shared__ int sh[1024];
    int tid = threadIdx.x;
    int i = blockIdx.x * 1024 + tid;
    int v = (i < N) ? deg[i] : 0;
    sh[tid] = v;
    __syncthreads();
    for (int off = 1; off < 1024; off <<= 1) {
        int t = (tid >= off) ? sh[tid - off] : 0;
        __syncthreads();
        sh[tid] += t;
        __syncthreads();
    }
    if (i < N) pre[i] = sh[tid] - v;              // exclusive
    if (tid == 1023) bsum[blockIdx.x] = sh[1023];
}

__global__ void scan_sums256(const int* bsum, int* boff, int nb) {
    __shared__ int sh[256];
    int tid = threadIdx.x;
    int v = (tid < nb) ? bsum[tid] : 0;
    sh[tid] = v;
    __syncthreads();
    for (int off = 1; off < 256; off <<= 1) {
        int t = (tid >= off) ? sh[tid - off] : 0;
        __syncthreads();
        sh[tid] += t;
        __syncthreads();
    }
    if (tid < nb) boff[tid] = sh[tid] - v;        // exclusive
}

__global__ void add_flat_kernel(int* a, const int* boff, int n) {
    int i = blockIdx.x * blockDim.x + threadIdx.x;
    if (i < n) a[i] += boff[i >> 10];
}

__global__ void shard_kernel(const int* __restrict__ src, const int* __restrict__ dst,
                             const float* __restrict__ ew, const int* __restrict__ scanT,
                             int2* __restrict__ perm2, int E, int EPB, int NBUK) {
    __shared__ int cur[MAXBUK];
    int eb = blockIdx.x;
    for (int i = threadIdx.x; i < NBUK; i += blockDim.x)
        cur[i] = scanT[i * EBLK + eb];
    __syncthreads();
    int lo = eb * EPB;
    int hi = lo + EPB; if (hi > E) hi = E;
    for (int e = lo + threadIdx.x; e < hi; e += blockDim.x) {
        int d = dst[e];
        int slot = atomicAdd(&cur[d >> 7], 1);
        int2 q;
        q.x = ((d & (BKL - 1)) << 20) | src[e];
        q.y = __float_as_int(ew[e]);
        perm2[slot] = q;
    }
}

__global__ void reorder_kernel(const int2* __restrict__ perm2,
                               const int* __restrict__ scanT,
                               int* __restrict__ cursor,
                               int2* __restrict__ perm, int E, int NBUK) {
    int b = blockIdx.x;
    int lo = scanT[b * EBLK];
    int hi = (b + 1 < NBUK) ? scanT[(b + 1) * EBLK] : E;
    int base = b * BKL;
    for (int j = lo + threadIdx.x; j < hi; j += blockDim.x) {
        int2 q = perm2[j];
        int d = base + (q.x >> 20);
        int slot = atomicAdd(&cursor[d], 1);
        int2 o;
        o.x = q.x & 0xFFFFF;
        o.y = q.y;
        perm[slot] = o;
    }
}

// ======================= node-level rowptr =================================

__global__ void hist_kernel(const int* dst, int* deg, int E) {
    int e = blockIdx.x * blockDim.x + threadIdx.x;
    if (e < E) atomicAdd(&deg[dst[e]], 1);
}

__global__ void add_off_kernel(int* rowptr, int* cursor, const int* boff, int N, int E) {
    int i = blockIdx.x * blockDim.x + threadIdx.x;
    if (i < N) {
        int v = rowptr[i] + boff[i >> 10];
        rowptr[i] = v;
        cursor[i] = v;
    }
    if (i == 0) rowptr[N] = E;
}

// ======================= gather: 64 lanes/node, 2 halves (r13/r14) =========
template <bool EMIT>
__global__ void gather2_kernel(const u16* __restrict__ xb,
                               const int* __restrict__ rowptr,
                               const int2* __restrict__ perm,
                               float* __restrict__ out,
                               u16* __restrict__ outb, int N) {
    int t = blockIdx.x * blockDim.x + threadIdx.x;
    int n = t >> 6;                               // 64 lanes per node
    if (n >= N) return;
    int lane = threadIdx.x & 63;
    int half = lane >> 5;
    int c = lane & 31;
    int b = rowptr[n], e = rowptr[n + 1];
    float a0 = 0.f, a1 = 0.f;
    int j = b + half;
    for (; j + 2 < e; j += 4) {
        int2 qa = perm[j];
        int2 qb = perm[j + 2];
        a0 += __int_as_float(qa.y) * bf16_to_f32(xb[qa.x * DD + c]);
        a1 += __int_as_float(qb.y) * bf16_to_f32(xb[qb.x * DD + c]);
    }
    if (j < e) {
        int2 q = perm[j];
        a0 += __int_as_float(q.y) * bf16_to_f32(xb[q.x * DD + c]);
    }
    float acc = a0 + a1;
    acc += __shfl_xor(acc, 32);
    if (half == 0) {
        out[n * DD + c] = acc;
        if (EMIT) outb[n * DD + c] = f32_to_bf16(acc);
    }
}

// ======================= combine v5: 64 lanes/node, split-K ================
// out[n][c] = sum_d x0*W0[d][c] + x1*W1[d][c] + x2*W2[d][c]
// Lane (c, half): 48 weights (3 x 16 K-values of its half) in registers —
// small enough that regalloc keeps them. 3 parallel 16-deep FMA chains,
// cross-half combine via shfl_xor(32). Bias dropped (BN cancels it).
// In-place on x0 safe: all of a wave's row loads precede its store.
__global__ __launch_bounds__(256, 4)
void combine_v5(const float* x0, const float* __restrict__ x1,
                const float* __restrict__ x2, const float* __restrict__ W,
                float* out, int N) {
    int lane = threadIdx.x & 63;
    int half = lane >> 5;                         // K-half: 0 -> d 0..15, 1 -> d 16..31
    int c = lane & 31;
    float w0[16], w1[16], w2[16];
#pragma unroll
    for (int k = 0; k < 16; ++k) {
        int d = half * 16 + k;
        w0[k] = W[d * DD + c];
        w1[k] = W[DD * DD + d * DD + c];
        w2[k] = W[2 * DD * DD + d * DD + c];
    }
    int wave   = (blockIdx.x * blockDim.x + threadIdx.x) >> 6;
    int nwaves = (gridDim.x * blockDim.x) >> 6;
    for (int n = wave; n < N; n += nwaves) {
        const float4* r0 = reinterpret_cast<const float4*>(x0 + (size_t)n * DD) + half * 4;
        const float4* r1 = reinterpret_cast<const float4*>(x1 + (size_t)n * DD) + half * 4;
        const float4* r2 = reinterpret_cast<const float4*>(x2 + (size_t)n * DD) + half * 4;
        float acc0 = 0.f, acc1 = 0.f, acc2 = 0.f;
#pragma unroll
        for (int q = 0; q < 4; ++q) {
            float4 v0 = r0[q];
            float4 v1 = r1[q];
            float4 v2 = r2[q];
            acc0 += v0.x * w0[4*q] + v0.y * w0[4*q+1] + v0.z * w0[4*q+2] + v0.w * w0[4*q+3];
            acc1 += v1.x * w1[4*q] + v1.y * w1[4*q+1] + v1.z * w1[4*q+2] + v1.w * w1[4*q+3];
            acc2 += v2.x * w2[4*q] + v2.y * w2[4*q+1] + v2.z * w2[4*q+2] + v2.w * w2[4*q+3];
        }
        float acc = acc0 + acc1 + acc2;
        acc += __shfl_xor(acc, 32);               // combine K-halves
        if (half == 0) out[(size_t)n * DD + c] = acc;
    }
}

// ======================= stats + bnrelu (proven) ===========================

__global__ void stats_part_kernel(const float* x, float* part, int total) {
    int tid = threadIdx.x;
    int idx = blockIdx.x * 256 + tid;
    const int stride = SB * 256;
    float s = 0.f, ss = 0.f;
    for (int i = idx; i < total; i += stride) { float v = x[i]; s += v; ss += v * v; }
    __shared__ float sh[2][8][DD];
    sh[0][tid >> 5][tid & 31] = s;
    sh[1][tid >> 5][tid & 31] = ss;
    __syncthreads();
    if (tid < DD) {
        float ts = 0.f, tss = 0.f;
        for (int g = 0; g < 8; ++g) { ts += sh[0][g][tid]; tss += sh[1][g][tid]; }
        part[blockIdx.x * 64 + tid] = ts;
        part[blockIdx.x * 64 + DD + tid] = tss;
    }
}

__global__ void stats_final_kernel(const float* part, float* st) {
    int tid = threadIdx.x;                        // 64 threads
    if (tid < 64) {
        float a = 0.f;
        for (int b = 0; b < SB; ++b) a += part[b * 64 + tid];
        st[tid] = a;
    }
}

template <bool EMIT>
__global__ void bnrelu_kernel(const float* x, const float* stats,
                              const float* gamma, const float* beta,
                              float* out, u16* outb, int total, float invN) {
    int i = blockIdx.x * blockDim.x + threadIdx.x;
    if (i >= total) return;
    int c = i & 31;
    float m   = stats[c] * invN;
    float msq = stats[DD + c] * invN;
    float var = msq - m * m;
    float inv = 1.0f / sqrtf(var + BN_EPS);
    float v = (x[i] - m) * inv * gamma[c] + beta[c];
    v = v >= 0.f ? v : NEG_SLOPE * v;
    out[i] = v;
    if (EMIT) outb[i] = f32_to_bf16(v);
}

// ======================= fallback path (round-3, proven) ===================

__global__ void prop_kernel(const float* x, const int* src, const int* dst,
                            const float* ew, float* out, int E) {
    int t = blockIdx.x * blockDim.x + threadIdx.x;
    int e = t >> 5;
    if (e >= E) return;
    int c = t & 31;
    float v = ew[e] * x[src[e] * DD + c];
    atomicAdd(&out[dst[e] * DD + c], v);
}

__global__ void combine_basic(const float* x0, const float* x1, const float* x2,
                              const float* W, const float* bias,
                              float* out, int N) {
    int t = blockIdx.x * blockDim.x + threadIdx.x;
    int n = t >> 5;
    if (n >= N) return;
    int c = t & 31;
    const float* r0 = x0 + n * DD;
    const float* r1 = x1 + n * DD;
    const float* r2 = x2 + n * DD;
    float acc = bias[c];
    for (int d = 0; d < DD; ++d) {
        acc += r0[d] * W[d * DD + c];
        acc += r1[d] * W[DD * DD + d * DD + c];
        acc += r2[d] * W[2 * DD * DD + d * DD + c];
    }
    out[t] = acc;
}

__global__ void stats_kernel(const float* x, float* stats, int N) {
    int c = blockIdx.x;
    int tid = threadIdx.x;
    float s = 0.f, ss = 0.f;
    for (int r = tid; r < N; r += 1024) {
        float v = x[r * DD + c];
        s += v; ss += v * v;
    }
    __shared__ float shs[1024];
    __shared__ float shq[1024];
    shs[tid] = s; shq[tid] = ss;
    __syncthreads();
    for (int off = 512; off > 0; off >>= 1) {
        if (tid < off) { shs[tid] += shs[tid + off]; shq[tid] += shq[tid + off]; }
        __syncthreads();
    }
    if (tid == 0) { stats[c] = shs[0]; stats[DD + c] = shq[0]; }
}

// ===========================================================================

extern "C" void kernel_launch(void* const* d_in, const int* in_sizes, int n_in,
                              void* d_out, int out_size, void* d_ws, size_t ws_size,
                              hipStream_t stream) {
    const float* y   = (const float*)d_in[0];
    const int*   ei  = (const int*)d_in[1];
    const float* ew  = (const float*)d_in[2];
    const float* W1  = (const float*)d_in[3];
    const float* b1  = (const float*)d_in[4];
    const float* g1  = (const float*)d_in[5];
    const float* be1 = (const float*)d_in[6];
    const float* W2  = (const float*)d_in[7];
    const float* b2  = (const float*)d_in[8];
    const float* g2  = (const float*)d_in[9];
    const float* be2 = (const float*)d_in[10];
    float* out = (float*)d_out;

    const int N = in_sizes[0] / DD;      // 100000
    const int E = in_sizes[2];           // 1600000
    const int total = N * DD;

    const int* src = ei;
    const int* dst = ei + E;

    const int NBUK = (N + BKL - 1) / BKL;         // 782
    const int TOTC = NBUK * EBLK;                 // 200192
    const int EPB  = (E + EBLK - 1) / EBLK;       // 6250
    const int NB2  = (TOTC + 1023) / 1024;        // 196
    const int NB   = (N + 1023) / 1024;           // 98

    // ws layout; RP multiple of 4 so perm stays 16B-aligned
    const int RP = (N + 4) & ~3;                  // 100004
    float* st     = (float*)d_ws;                 // 128 f
    float* h1     = st + 128;                     // total f
    float* h2     = h1 + total;                   // total f
    int*   rowptr = (int*)(h2 + total);           // RP i
    int2*  perm   = (int2*)(rowptr + RP);         // E int2 (node-ordered CSR)
    char*  tail   = (char*)(perm + E);
    u16*   h1b    = (u16*)tail;                   // total u16 (gather phase)
    float* part   = (float*)tail;                 // SB*64 f (stats phase)
    int*   scanT  = (int*)tail;                   // TOTC i (build phase)
    // build-phase aliases:
    int2*  perm2  = (int2*)h1;                    // E int2 == total f exactly
    u16*   xb16   = (u16*)h2;                     // bf16 rows (after build)
    int*   deg    = (int*)h2;                     // N i
    int*   cursor = deg + N;                      // N i
    int*   bsum   = deg + 2 * N;                  // 256 i
    int*   boff   = bsum + 256;                   // 256 i

    size_t tailBytes = (size_t)total * 2;
    if ((size_t)SB * 64 * 4 > tailBytes) tailBytes = (size_t)SB * 64 * 4;
    if ((size_t)TOTC * 4 > tailBytes)    tailBytes = (size_t)TOTC * 4;
    const size_t need = ((size_t)128 + 2 * (size_t)total + RP + 2 * (size_t)E) * 4 + tailBytes;
    const bool fast = (ws_size >= need) && (NBUK <= MAXBUK) && (N <= (1 << 20));

    const float invN = 1.0f / (float)N;
    dim3 blk(256);
    const int ngrid = (N + 255) / 256;
    const int egrid = (E + 255) / 256;
    const int cgrid = (total + 255) / 256;
    const int ggrid = (2 * total + 255) / 256;    // 64 lanes per node
    const int fgrid = (TOTC + 255) / 256;
    const int zgrid = (2 * total + 255) / 256;
    const int pgrid = (E * DD + 255) / 256;
    const int vgrid = 2048;                       // persistent combine_v5 grid

    if (fast) {
        // ---- bucket counting sort: count -> scan -> shard (write-local) ----
        count_kernel<<<EBLK, blk, 0, stream>>>(dst, scanT, E, EPB, NBUK);
        scan_block_kernel<<<NB2, 1024, 0, stream>>>(scanT, scanT, bsum, TOTC);
        scan_sums256<<<1, 256, 0, stream>>>(bsum, boff, NB2);
        add_flat_kernel<<<fgrid, blk, 0, stream>>>(scanT, boff, TOTC);
        shard_kernel<<<EBLK, blk, 0, stream>>>(src, dst, ew, scanT, perm2, E, EPB, NBUK);

        // ---- node-level rowptr + cursor ----
        zero_int_kernel<<<ngrid, blk, 0, stream>>>(deg, N);
        hist_kernel<<<egrid, blk, 0, stream>>>(dst, deg, E);
        scan_block_kernel<<<NB, 1024, 0, stream>>>(deg, rowptr, bsum, N);
        scan_sums256<<<1, 256, 0, stream>>>(bsum, boff, NB);
        add_off_kernel<<<ngrid, blk, 0, stream>>>(rowptr, cursor, boff, N, E);

        // ---- bucket-local reorder into node-ordered perm ----
        reorder_kernel<<<NBUK, blk, 0, stream>>>(perm2, scanT, cursor, perm, E, NBUK);

        // ---- layer 1 ----
        cvt_bf16_kernel<<<cgrid, blk, 0, stream>>>(y, xb16, total);   // overwrites deg/cursor (dead)
        gather2_kernel<true><<<ggrid, blk, 0, stream>>>(xb16, rowptr, perm, h1, h1b, N);  // h1 over perm2 (dead), h1b over scanT (dead)
        gather2_kernel<false><<<ggrid, blk, 0, stream>>>(h1b, rowptr, perm, h2, nullptr, N);
        combine_v5<<<vgrid, blk, 0, stream>>>(y, h1, h2, W1, out, N);
        stats_part_kernel<<<SB, blk, 0, stream>>>(out, part, total);
        stats_final_kernel<<<1, 64, 0, stream>>>(part, st);
        bnrelu_kernel<true><<<cgrid, blk, 0, stream>>>(out, st, g1, be1, out, xb16, total, invN);

        // ---- layer 2 ----
        gather2_kernel<true><<<ggrid, blk, 0, stream>>>(xb16, rowptr, perm, h1, h1b, N);
        gather2_kernel<false><<<ggrid, blk, 0, stream>>>(h1b, rowptr, perm, h2, nullptr, N);
        combine_v5<<<vgrid, blk, 0, stream>>>(out, h1, h2, W2, out, N);
        stats_part_kernel<<<SB, blk, 0, stream>>>(out, part, total);
        stats_final_kernel<<<1, 64, 0, stream>>>(part, st + 64);
        bnrelu_kernel<false><<<cgrid, blk, 0, stream>>>(out, st + 64, g2, be2, out, nullptr, total, invN);
    } else {
        // ---- fallback: round-3 proven scatter path ----
        zero_kernel<<<zgrid, blk, 0, stream>>>(h1, 2 * total);
        prop_kernel<<<pgrid, blk, 0, stream>>>(y,  src, dst, ew, h1, E);
        prop_kernel<<<pgrid, blk, 0, stream>>>(h1, src, dst, ew, h2, E);
        combine_basic<<<cgrid, blk, 0, stream>>>(y, h1, h2, W1, b1, out, N);
        stats_kernel<<<32, 1024, 0, stream>>>(out, st, N);
        bnrelu_kernel<false><<<cgrid, blk, 0, stream>>>(out, st, g1, be1, out, nullptr, total, invN);

        zero_kernel<<<zgrid, blk, 0, stream>>>(h1, 2 * total);
        prop_kernel<<<pgrid, blk, 0, stream>>>(out, src, dst, ew, h1, E);
        prop_kernel<<<pgrid, blk, 0, stream>>>(h1,  src, dst, ew, h2, E);
        combine_basic<<<cgrid, blk, 0, stream>>>(out, h1, h2, W2, b2, out, N);
        stats_kernel<<<32, 1024, 0, stream>>>(out, st + 2 * DD, N);
        bnrelu_kernel<false><<<cgrid, blk, 0, stream>>>(out, st + 2 * DD, g2, be2, out, nullptr, total, invN);
    }
}